// Round 3
// baseline (136.741 us; speedup 1.0000x reference)
//
#include <hip/hip_runtime.h>
#include <hip/hip_bf16.h>

#define NN 100000       // nodes
#define DD 128          // emb dim (PQ width: 64 P + 64 Q)
#define EHn 400000      // half-edge count
#define BIASc 1e-4f
#define NBLK_EDGE 1563  // ceil(400000/256)

using bf16x8 = __attribute__((ext_vector_type(8))) __bf16;
using f32x4  = __attribute__((ext_vector_type(4))) float;

// workspace layout
#define PQ_OFF    0
#define PQ_BYTES  ((size_t)NN * DD * 2)          // 25,600,000 B
#define PART_OFF  PQ_BYTES
#define CNT_OFF   (PART_OFF + NBLK_EDGE * 4)

// ---------------------------------------------------------------------------
// Kernel 1: PQ = emb @ W1cat (+ b1 folded into P cols). bf16 MFMA, fp32 acc.
// Each block first builds the 32 B-fragments (16K bf16 = 32 KB) in LDS from
// W1 (fp32 [256][64] row-major, L2-hot). W1cat[k][c]: c<64 -> W1[k][c],
// c>=64 -> W1[k+128][c-64]. Frag (t,f), lane l, j: k=t*32+(l>>4)*8+j,
// c=f*16+(l&15); flat LDS entry = (t*8+f)*64 + l  (8 bf16 each).
// Also zeroes the edge-kernel completion counter (block 0).
// ---------------------------------------------------------------------------
__global__ __launch_bounds__(256)
void node_proj_kernel(const float* __restrict__ emb, const float* __restrict__ W1,
                      const float* __restrict__ b1, __bf16* __restrict__ PQ,
                      unsigned* __restrict__ cnt) {
    if (blockIdx.x == 0 && threadIdx.x == 0) *cnt = 0u;   // visible to edge kernel via stream order

    __shared__ __bf16 sfrag[16384];                        // 32 KB
    #pragma unroll
    for (int i = 0; i < 8; ++i) {
        int e = threadIdx.x + i * 256;                     // 0..2047
        int l = e & 63;
        int f = (e >> 6) & 7;
        int t = e >> 9;
        int c = f * 16 + (l & 15);
        const float* wcol = (c < 64) ? (W1 + c) : (W1 + 128 * 64 + (c - 64));
        int kbase = t * 32 + ((l >> 4) << 3);
        bf16x8 v;
        #pragma unroll
        for (int j = 0; j < 8; ++j)
            v[j] = (__bf16)wcol[(kbase + j) * 64];
        *(bf16x8*)(&sfrag[(size_t)e * 8]) = v;
    }
    __syncthreads();

    const int lane = threadIdx.x & 63;
    const int wave = threadIdx.x >> 6;
    const int rowBase = blockIdx.x * 128 + wave * 32;
    const int r16 = lane & 15;
    const int kg  = lane >> 4;

    f32x4 acc[2][8];
    #pragma unroll
    for (int m = 0; m < 2; ++m)
        #pragma unroll
        for (int f = 0; f < 8; ++f)
            acc[m][f] = (f32x4){0.f, 0.f, 0.f, 0.f};

    const bf16x8* sfragV = (const bf16x8*)sfrag;

    #pragma unroll
    for (int t = 0; t < 4; ++t) {
        bf16x8 af[2];
        #pragma unroll
        for (int m = 0; m < 2; ++m) {
            int row = rowBase + m * 16 + r16;
            row = row < NN ? row : NN - 1;        // clamp tail (stores guarded)
            const float* ap = emb + (size_t)row * DD + t * 32 + kg * 8;
            float4 lo = *(const float4*)ap;
            float4 hi = *(const float4*)(ap + 4);
            bf16x8 v;
            v[0] = (__bf16)lo.x; v[1] = (__bf16)lo.y; v[2] = (__bf16)lo.z; v[3] = (__bf16)lo.w;
            v[4] = (__bf16)hi.x; v[5] = (__bf16)hi.y; v[6] = (__bf16)hi.z; v[7] = (__bf16)hi.w;
            af[m] = v;
        }
        #pragma unroll
        for (int f = 0; f < 8; ++f) {
            bf16x8 bf = sfragV[(t * 8 + f) * 64 + lane];
            #pragma unroll
            for (int m = 0; m < 2; ++m)
                acc[m][f] = __builtin_amdgcn_mfma_f32_16x16x32_bf16(af[m], bf, acc[m][f], 0, 0, 0);
        }
    }

    // C/D layout: col = lane&15, row = (lane>>4)*4 + r. Fold b1 into P cols.
    #pragma unroll
    for (int m = 0; m < 2; ++m) {
        #pragma unroll
        for (int f = 0; f < 8; ++f) {
            #pragma unroll
            for (int r = 0; r < 4; ++r) {
                int row = rowBase + m * 16 + kg * 4 + r;
                int col = f * 16 + r16;
                float v = acc[m][f][r];
                if (col < 64) v += b1[col];
                if (row < NN) PQ[(size_t)row * DD + col] = (__bf16)v;
            }
        }
    }
}

// ---------------------------------------------------------------------------
// Kernel 2: per-edge gate, ONE LANE PER EDGE + fused mean.
// Lane: gather P-row/Q-row (128 B each), lane-local relu-dot with W2
// (SGPR-uniform), concrete gate, two coalesced stores. Block partials ->
// last-block-done deterministic reduction writes out[2*EHn].
// ---------------------------------------------------------------------------
__global__ __launch_bounds__(256)
void edge_kernel(const __bf16* __restrict__ PQ, const int* __restrict__ src,
                 const int* __restrict__ dst, const float* __restrict__ vals,
                 const float* __restrict__ eps_u, const float* __restrict__ W2,
                 const float* __restrict__ b2, float* __restrict__ out,
                 float* __restrict__ partials, unsigned* __restrict__ cnt) {
    const int e = blockIdx.x * 256 + threadIdx.x;
    float wgate = 0.f;

    if (e < EHn) {
        const int s = src[e];
        const int d = dst[e];
        const uint4* prow = (const uint4*)(PQ + (size_t)s * DD);        // P half (+b1)
        const uint4* qrow = (const uint4*)(PQ + (size_t)d * DD + 64);   // Q half

        float acc0 = 0.f, acc1 = 0.f;
        #pragma unroll
        for (int c = 0; c < 8; ++c) {
            uint4 p = prow[c];
            uint4 q = qrow[c];
            const unsigned pw[4] = {p.x, p.y, p.z, p.w};
            const unsigned qw[4] = {q.x, q.y, q.z, q.w};
            #pragma unroll
            for (int k = 0; k < 4; ++k) {
                int i = c * 8 + k * 2;
                float pl = __uint_as_float(pw[k] << 16);
                float ph = __uint_as_float(pw[k] & 0xffff0000u);
                float ql = __uint_as_float(qw[k] << 16);
                float qh = __uint_as_float(qw[k] & 0xffff0000u);
                acc0 = fmaf(fmaxf(pl + ql, 0.f), W2[i], acc0);
                acc1 = fmaf(fmaxf(ph + qh, 0.f), W2[i + 1], acc1);
            }
        }
        float logit = acc0 + acc1 + b2[0];

        float u = eps_u[e];
        float epsv = fmaf(2.f * BIASc - 1.f, u, 1.f - BIASc);   // eps in [BIAS, 1-BIAS]
        float ome  = fmaf(1.f - 2.f * BIASc, u, BIASc);         // 1 - eps (no cancellation)
        float g = __logf(epsv) - __logf(ome) + logit;           // TEMP = 1
        wgate = 1.f / (1.f + __expf(-g));
        float nv = vals[e] * wgate;
        out[e] = nv;
        out[EHn + e] = nv;
    }

    // block reduction of gate weights -> partials[block]
    __shared__ float sred[256];
    __shared__ int lastFlag;
    sred[threadIdx.x] = wgate;
    __syncthreads();
    #pragma unroll
    for (int st = 128; st >= 64; st >>= 1) {
        if ((int)threadIdx.x < st) sred[threadIdx.x] += sred[threadIdx.x + st];
        __syncthreads();
    }
    if (threadIdx.x < 64) {
        float a = sred[threadIdx.x];
        #pragma unroll
        for (int off = 32; off > 0; off >>= 1)
            a += __shfl_xor(a, off, 64);
        if (threadIdx.x == 0) {
            __hip_atomic_store(&partials[blockIdx.x], a, __ATOMIC_RELEASE,
                               __HIP_MEMORY_SCOPE_AGENT);
            unsigned old = __hip_atomic_fetch_add(cnt, 1u, __ATOMIC_ACQ_REL,
                                                  __HIP_MEMORY_SCOPE_AGENT);
            lastFlag = (old == NBLK_EDGE - 1);
        }
    }
    __syncthreads();

    if (lastFlag) {       // exactly one block: deterministic final reduction
        float a = 0.f;
        for (int i = threadIdx.x; i < NBLK_EDGE; i += 256)
            a += __hip_atomic_load(&partials[i], __ATOMIC_RELAXED,
                                   __HIP_MEMORY_SCOPE_AGENT);
        __syncthreads();
        sred[threadIdx.x] = a;
        __syncthreads();
        #pragma unroll
        for (int st = 128; st > 0; st >>= 1) {
            if ((int)threadIdx.x < st) sred[threadIdx.x] += sred[threadIdx.x + st];
            __syncthreads();
        }
        if (threadIdx.x == 0) out[2 * EHn] = sred[0] / (float)EHn;
    }
}

extern "C" void kernel_launch(void* const* d_in, const int* in_sizes, int n_in,
                              void* d_out, int out_size, void* d_ws, size_t ws_size,
                              hipStream_t stream) {
    const float* emb  = (const float*)d_in[0];
    const int*   src  = (const int*)d_in[1];
    const int*   dst  = (const int*)d_in[2];
    const float* vals = (const float*)d_in[3];
    const float* eps  = (const float*)d_in[4];
    const float* W1   = (const float*)d_in[5];
    const float* b1   = (const float*)d_in[6];
    const float* W2   = (const float*)d_in[7];
    const float* b2   = (const float*)d_in[8];
    float* out = (float*)d_out;

    char* ws = (char*)d_ws;
    __bf16*   PQ       = (__bf16*)(ws + PQ_OFF);
    float*    partials = (float*)(ws + PART_OFF);
    unsigned* cnt      = (unsigned*)(ws + CNT_OFF);

    hipLaunchKernelGGL(node_proj_kernel, dim3((NN + 127) / 128), dim3(256), 0, stream,
                       emb, W1, b1, PQ, cnt);
    hipLaunchKernelGGL(edge_kernel, dim3(NBLK_EDGE), dim3(256), 0, stream,
                       PQ, src, dst, vals, eps, W2, b2, out, partials, cnt);
}

// Round 4
// 52.282 us; speedup vs baseline: 2.6154x; 2.6154x over previous
//
#include <hip/hip_runtime.h>
#include <hip/hip_bf16.h>

#define NN 100000       // nodes
#define DD 128          // emb dim (PQ width: 64 P + 64 Q)
#define EHn 400000      // half-edge count
#define BIASc 1e-4f
#define NBLK_EDGE 1563  // ceil(400000/256)

using bf16x8 = __attribute__((ext_vector_type(8))) __bf16;
using f32x4  = __attribute__((ext_vector_type(4))) float;

// workspace layout
#define PQ_OFF    0
#define PQ_BYTES  ((size_t)NN * DD * 2)          // 25,600,000 B
#define PART_OFF  PQ_BYTES

// ---------------------------------------------------------------------------
// Kernel 1: PQ = emb @ W1cat (+ b1 folded into P cols). bf16 MFMA, fp32 acc.
// Each block first builds the 32 B-fragments (16K bf16 = 32 KB) in LDS from
// W1 (fp32 [256][64] row-major, L2-hot). W1cat[k][c]: c<64 -> W1[k][c],
// c>=64 -> W1[k+128][c-64]. Frag (t,f), lane l, j: k=t*32+(l>>4)*8+j,
// c=f*16+(l&15); flat LDS entry = (t*8+f)*64 + l  (8 bf16 each).
// ---------------------------------------------------------------------------
__global__ __launch_bounds__(256)
void node_proj_kernel(const float* __restrict__ emb, const float* __restrict__ W1,
                      const float* __restrict__ b1, __bf16* __restrict__ PQ) {
    __shared__ __bf16 sfrag[16384];                        // 32 KB
    #pragma unroll
    for (int i = 0; i < 8; ++i) {
        int e = threadIdx.x + i * 256;                     // 0..2047
        int l = e & 63;
        int f = (e >> 6) & 7;
        int t = e >> 9;
        int c = f * 16 + (l & 15);
        const float* wcol = (c < 64) ? (W1 + c) : (W1 + 128 * 64 + (c - 64));
        int kbase = t * 32 + ((l >> 4) << 3);
        bf16x8 v;
        #pragma unroll
        for (int j = 0; j < 8; ++j)
            v[j] = (__bf16)wcol[(kbase + j) * 64];
        *(bf16x8*)(&sfrag[(size_t)e * 8]) = v;
    }
    __syncthreads();

    const int lane = threadIdx.x & 63;
    const int wave = threadIdx.x >> 6;
    const int rowBase = blockIdx.x * 128 + wave * 32;
    const int r16 = lane & 15;
    const int kg  = lane >> 4;

    f32x4 acc[2][8];
    #pragma unroll
    for (int m = 0; m < 2; ++m)
        #pragma unroll
        for (int f = 0; f < 8; ++f)
            acc[m][f] = (f32x4){0.f, 0.f, 0.f, 0.f};

    const bf16x8* sfragV = (const bf16x8*)sfrag;

    #pragma unroll
    for (int t = 0; t < 4; ++t) {
        bf16x8 af[2];
        #pragma unroll
        for (int m = 0; m < 2; ++m) {
            int row = rowBase + m * 16 + r16;
            row = row < NN ? row : NN - 1;        // clamp tail (stores guarded)
            const float* ap = emb + (size_t)row * DD + t * 32 + kg * 8;
            float4 lo = *(const float4*)ap;
            float4 hi = *(const float4*)(ap + 4);
            bf16x8 v;
            v[0] = (__bf16)lo.x; v[1] = (__bf16)lo.y; v[2] = (__bf16)lo.z; v[3] = (__bf16)lo.w;
            v[4] = (__bf16)hi.x; v[5] = (__bf16)hi.y; v[6] = (__bf16)hi.z; v[7] = (__bf16)hi.w;
            af[m] = v;
        }
        #pragma unroll
        for (int f = 0; f < 8; ++f) {
            bf16x8 bf = sfragV[(t * 8 + f) * 64 + lane];
            #pragma unroll
            for (int m = 0; m < 2; ++m)
                acc[m][f] = __builtin_amdgcn_mfma_f32_16x16x32_bf16(af[m], bf, acc[m][f], 0, 0, 0);
        }
    }

    // C/D layout: col = lane&15, row = (lane>>4)*4 + r. Fold b1 into P cols.
    #pragma unroll
    for (int m = 0; m < 2; ++m) {
        #pragma unroll
        for (int f = 0; f < 8; ++f) {
            #pragma unroll
            for (int r = 0; r < 4; ++r) {
                int row = rowBase + m * 16 + kg * 4 + r;
                int col = f * 16 + r16;
                float v = acc[m][f][r];
                if (col < 64) v += b1[col];
                if (row < NN) PQ[(size_t)row * DD + col] = (__bf16)v;
            }
        }
    }
}

// ---------------------------------------------------------------------------
// Kernel 2: per-edge gate. ONE LANE PER EDGE. Lane loads its P-row (128B) and
// Q-row (128B), lane-local relu-dot with W2 (SGPR-uniform), concrete gate,
// two coalesced stores, block partial sum via LDS only (no device atomics —
// R3 showed agent-scope atomics cost ~100 µs in L2 flushes on this chip).
// ---------------------------------------------------------------------------
__global__ __launch_bounds__(256)
void edge_kernel(const __bf16* __restrict__ PQ, const int* __restrict__ src,
                 const int* __restrict__ dst, const float* __restrict__ vals,
                 const float* __restrict__ eps_u, const float* __restrict__ W2,
                 const float* __restrict__ b2, float* __restrict__ out,
                 float* __restrict__ partials) {
    const int e = blockIdx.x * 256 + threadIdx.x;
    float wgate = 0.f;

    if (e < EHn) {
        const int s = src[e];
        const int d = dst[e];
        const uint4* prow = (const uint4*)(PQ + (size_t)s * DD);        // P half (+b1)
        const uint4* qrow = (const uint4*)(PQ + (size_t)d * DD + 64);   // Q half

        float acc0 = 0.f, acc1 = 0.f;
        #pragma unroll
        for (int c = 0; c < 8; ++c) {
            uint4 p = prow[c];
            uint4 q = qrow[c];
            const unsigned pw[4] = {p.x, p.y, p.z, p.w};
            const unsigned qw[4] = {q.x, q.y, q.z, q.w};
            #pragma unroll
            for (int k = 0; k < 4; ++k) {
                int i = c * 8 + k * 2;
                float pl = __uint_as_float(pw[k] << 16);
                float ph = __uint_as_float(pw[k] & 0xffff0000u);
                float ql = __uint_as_float(qw[k] << 16);
                float qh = __uint_as_float(qw[k] & 0xffff0000u);
                acc0 = fmaf(fmaxf(pl + ql, 0.f), W2[i], acc0);
                acc1 = fmaf(fmaxf(ph + qh, 0.f), W2[i + 1], acc1);
            }
        }
        float logit = acc0 + acc1 + b2[0];

        float u = eps_u[e];
        float epsv = fmaf(2.f * BIASc - 1.f, u, 1.f - BIASc);   // eps in [BIAS, 1-BIAS]
        float ome  = fmaf(1.f - 2.f * BIASc, u, BIASc);         // 1 - eps (no cancellation)
        float g = __logf(epsv) - __logf(ome) + logit;           // TEMP = 1
        wgate = 1.f / (1.f + __expf(-g));
        float nv = vals[e] * wgate;
        out[e] = nv;
        out[EHn + e] = nv;
    }

    // block reduction of gate weights -> partials[block]
    __shared__ float sred[256];
    sred[threadIdx.x] = wgate;
    __syncthreads();
    #pragma unroll
    for (int st = 128; st >= 64; st >>= 1) {
        if ((int)threadIdx.x < st) sred[threadIdx.x] += sred[threadIdx.x + st];
        __syncthreads();
    }
    if (threadIdx.x < 64) {
        float a = sred[threadIdx.x];
        #pragma unroll
        for (int off = 32; off > 0; off >>= 1)
            a += __shfl_xor(a, off, 64);
        if (threadIdx.x == 0) partials[blockIdx.x] = a;
    }
}

// ---------------------------------------------------------------------------
// Kernel 3: deterministic mean reduction over block partials.
// ---------------------------------------------------------------------------
__global__ void mean_kernel(const float* __restrict__ partials, float* __restrict__ out) {
    __shared__ float s[256];
    float a = 0.f;
    for (int i = threadIdx.x; i < NBLK_EDGE; i += 256) a += partials[i];
    s[threadIdx.x] = a;
    __syncthreads();
    for (int st = 128; st > 0; st >>= 1) {
        if ((int)threadIdx.x < st) s[threadIdx.x] += s[threadIdx.x + st];
        __syncthreads();
    }
    if (threadIdx.x == 0) out[2 * EHn] = s[0] / (float)EHn;
}

extern "C" void kernel_launch(void* const* d_in, const int* in_sizes, int n_in,
                              void* d_out, int out_size, void* d_ws, size_t ws_size,
                              hipStream_t stream) {
    const float* emb  = (const float*)d_in[0];
    const int*   src  = (const int*)d_in[1];
    const int*   dst  = (const int*)d_in[2];
    const float* vals = (const float*)d_in[3];
    const float* eps  = (const float*)d_in[4];
    const float* W1   = (const float*)d_in[5];
    const float* b1   = (const float*)d_in[6];
    const float* W2   = (const float*)d_in[7];
    const float* b2   = (const float*)d_in[8];
    float* out = (float*)d_out;

    char* ws = (char*)d_ws;
    __bf16* PQ       = (__bf16*)(ws + PQ_OFF);
    float*  partials = (float*)(ws + PART_OFF);

    hipLaunchKernelGGL(node_proj_kernel, dim3((NN + 127) / 128), dim3(256), 0, stream,
                       emb, W1, b1, PQ);
    hipLaunchKernelGGL(edge_kernel, dim3(NBLK_EDGE), dim3(256), 0, stream,
                       PQ, src, dst, vals, eps, W2, b2, out, partials);
    hipLaunchKernelGGL(mean_kernel, dim3(1), dim3(256), 0, stream, partials, out);
}

// Round 5
// 46.989 us; speedup vs baseline: 2.9101x; 1.1127x over previous
//
#include <hip/hip_runtime.h>
#include <hip/hip_bf16.h>

#define NN 100000       // nodes
#define DD 128          // emb dim (PQ width: 64 P + 64 Q)
#define EHn 400000      // half-edge count
#define BIASc 1e-4f
#define NBLK_EDGE 1563  // ceil(400000/256)

using bf16x8 = __attribute__((ext_vector_type(8))) __bf16;
using f32x4  = __attribute__((ext_vector_type(4))) float;

// workspace layout
#define PQ_OFF    0
#define PQ_BYTES  ((size_t)NN * DD * 2)          // 25,600,000 B
#define PART_OFF  PQ_BYTES

// ---------------------------------------------------------------------------
// Kernel 1: PQ = emb @ W1cat (+ b1 folded into P cols). bf16 MFMA, fp32 acc.
// Each block first builds the 32 B-fragments (16K bf16 = 32 KB) in LDS from
// W1 (fp32 [256][64] row-major, L2-hot). W1cat[k][c]: c<64 -> W1[k][c],
// c>=64 -> W1[k+128][c-64]. Frag (t,f), lane l, j: k=t*32+(l>>4)*8+j,
// c=f*16+(l&15); flat LDS entry = (t*8+f)*64 + l  (8 bf16 each).
// ---------------------------------------------------------------------------
__global__ __launch_bounds__(256)
void node_proj_kernel(const float* __restrict__ emb, const float* __restrict__ W1,
                      const float* __restrict__ b1, __bf16* __restrict__ PQ) {
    __shared__ __bf16 sfrag[16384];                        // 32 KB
    #pragma unroll
    for (int i = 0; i < 8; ++i) {
        int e = threadIdx.x + i * 256;                     // 0..2047
        int l = e & 63;
        int f = (e >> 6) & 7;
        int t = e >> 9;
        int c = f * 16 + (l & 15);
        const float* wcol = (c < 64) ? (W1 + c) : (W1 + 128 * 64 + (c - 64));
        int kbase = t * 32 + ((l >> 4) << 3);
        bf16x8 v;
        #pragma unroll
        for (int j = 0; j < 8; ++j)
            v[j] = (__bf16)wcol[(kbase + j) * 64];
        *(bf16x8*)(&sfrag[(size_t)e * 8]) = v;
    }
    __syncthreads();

    const int lane = threadIdx.x & 63;
    const int wave = threadIdx.x >> 6;
    const int rowBase = blockIdx.x * 128 + wave * 32;
    const int r16 = lane & 15;
    const int kg  = lane >> 4;

    f32x4 acc[2][8];
    #pragma unroll
    for (int m = 0; m < 2; ++m)
        #pragma unroll
        for (int f = 0; f < 8; ++f)
            acc[m][f] = (f32x4){0.f, 0.f, 0.f, 0.f};

    const bf16x8* sfragV = (const bf16x8*)sfrag;

    #pragma unroll
    for (int t = 0; t < 4; ++t) {
        bf16x8 af[2];
        #pragma unroll
        for (int m = 0; m < 2; ++m) {
            int row = rowBase + m * 16 + r16;
            row = row < NN ? row : NN - 1;        // clamp tail (stores guarded)
            const float* ap = emb + (size_t)row * DD + t * 32 + kg * 8;
            float4 lo = *(const float4*)ap;
            float4 hi = *(const float4*)(ap + 4);
            bf16x8 v;
            v[0] = (__bf16)lo.x; v[1] = (__bf16)lo.y; v[2] = (__bf16)lo.z; v[3] = (__bf16)lo.w;
            v[4] = (__bf16)hi.x; v[5] = (__bf16)hi.y; v[6] = (__bf16)hi.z; v[7] = (__bf16)hi.w;
            af[m] = v;
        }
        #pragma unroll
        for (int f = 0; f < 8; ++f) {
            bf16x8 bf = sfragV[(t * 8 + f) * 64 + lane];
            #pragma unroll
            for (int m = 0; m < 2; ++m)
                acc[m][f] = __builtin_amdgcn_mfma_f32_16x16x32_bf16(af[m], bf, acc[m][f], 0, 0, 0);
        }
    }

    // C/D layout: col = lane&15, row = (lane>>4)*4 + r. Fold b1 into P cols.
    #pragma unroll
    for (int m = 0; m < 2; ++m) {
        #pragma unroll
        for (int f = 0; f < 8; ++f) {
            #pragma unroll
            for (int r = 0; r < 4; ++r) {
                int row = rowBase + m * 16 + kg * 4 + r;
                int col = f * 16 + r16;
                float v = acc[m][f][r];
                if (col < 64) v += b1[col];
                if (row < NN) PQ[(size_t)row * DD + col] = (__bf16)v;
            }
        }
    }
}

// ---------------------------------------------------------------------------
// Kernel 2: per-edge gate, 8 LANES PER EDGE (cooperative line gather).
// P-half and Q-half of a PQ row are each exactly one 128-B cache line; 8
// lanes fetch 16 B chunks so every load instruction consumes 8 whole lines
// (no L1-retention dependence, unlike lane-per-edge). Each lane dots its 8
// hidden units with its W2 chunk; 3-level shfl_xor reduces within the group;
// lane k==0 applies the concrete gate and stores. 8 passes x 8 edges per
// wave -> 256 edges per block. Block partials via LDS only (no atomics).
// ---------------------------------------------------------------------------
__global__ __launch_bounds__(256)
void edge_kernel(const __bf16* __restrict__ PQ, const int* __restrict__ src,
                 const int* __restrict__ dst, const float* __restrict__ vals,
                 const float* __restrict__ eps_u, const float* __restrict__ W2,
                 const float* __restrict__ b2, float* __restrict__ out,
                 float* __restrict__ partials) {
    const int lane = threadIdx.x & 63;
    const int wv   = threadIdx.x >> 6;
    const int k    = lane & 7;        // 16-B chunk within row (8 hidden units)
    const int g    = lane >> 3;       // edge-group within wave (0..7)

    // per-lane W2 chunk: hidden units k*8 .. k*8+7
    float4 wa = *(const float4*)(W2 + k * 8);
    float4 wb = *(const float4*)(W2 + k * 8 + 4);
    const float w2v[8] = {wa.x, wa.y, wa.z, wa.w, wb.x, wb.y, wb.z, wb.w};
    const float b2s = b2[0];

    const int waveBase = blockIdx.x * 256 + wv * 64;   // this wave's 64 edges
    float wsum = 0.f;                                  // nonzero only on k==0 lanes

    #pragma unroll
    for (int pass = 0; pass < 8; ++pass) {
        const int e = waveBase + pass * 8 + g;
        const bool valid = e < EHn;
        const int s = valid ? src[e] : 0;
        const int d = valid ? dst[e] : 0;

        uint4 p = *(const uint4*)(PQ + (size_t)s * DD + k * 8);        // P chunk (+b1)
        uint4 q = *(const uint4*)(PQ + (size_t)d * DD + 64 + k * 8);   // Q chunk

        const unsigned pw[4] = {p.x, p.y, p.z, p.w};
        const unsigned qw[4] = {q.x, q.y, q.z, q.w};
        float acc = 0.f;
        #pragma unroll
        for (int w = 0; w < 4; ++w) {
            float pl = __uint_as_float(pw[w] << 16);
            float ph = __uint_as_float(pw[w] & 0xffff0000u);
            float ql = __uint_as_float(qw[w] << 16);
            float qh = __uint_as_float(qw[w] & 0xffff0000u);
            acc = fmaf(fmaxf(pl + ql, 0.f), w2v[w * 2], acc);
            acc = fmaf(fmaxf(ph + qh, 0.f), w2v[w * 2 + 1], acc);
        }
        acc += __shfl_xor(acc, 1, 64);
        acc += __shfl_xor(acc, 2, 64);
        acc += __shfl_xor(acc, 4, 64);

        if (k == 0 && valid) {
            float logit = acc + b2s;
            float u = eps_u[e];
            float epsv = fmaf(2.f * BIASc - 1.f, u, 1.f - BIASc);   // eps
            float ome  = fmaf(1.f - 2.f * BIASc, u, BIASc);         // 1 - eps
            float gg = __logf(epsv) - __logf(ome) + logit;          // TEMP = 1
            float wgate = 1.f / (1.f + __expf(-gg));
            float nv = vals[e] * wgate;
            out[e] = nv;
            out[EHn + e] = nv;
            wsum += wgate;
        }
    }

    // block reduction of gate weights -> partials[block]
    __shared__ float sred[256];
    sred[threadIdx.x] = wsum;
    __syncthreads();
    #pragma unroll
    for (int st = 128; st >= 64; st >>= 1) {
        if ((int)threadIdx.x < st) sred[threadIdx.x] += sred[threadIdx.x + st];
        __syncthreads();
    }
    if (threadIdx.x < 64) {
        float a = sred[threadIdx.x];
        #pragma unroll
        for (int off = 32; off > 0; off >>= 1)
            a += __shfl_xor(a, off, 64);
        if (threadIdx.x == 0) partials[blockIdx.x] = a;
    }
}

// ---------------------------------------------------------------------------
// Kernel 3: deterministic mean reduction over block partials.
// ---------------------------------------------------------------------------
__global__ void mean_kernel(const float* __restrict__ partials, float* __restrict__ out) {
    __shared__ float s[256];
    float a = 0.f;
    for (int i = threadIdx.x; i < NBLK_EDGE; i += 256) a += partials[i];
    s[threadIdx.x] = a;
    __syncthreads();
    for (int st = 128; st > 0; st >>= 1) {
        if ((int)threadIdx.x < st) s[threadIdx.x] += s[threadIdx.x + st];
        __syncthreads();
    }
    if (threadIdx.x == 0) out[2 * EHn] = s[0] / (float)EHn;
}

extern "C" void kernel_launch(void* const* d_in, const int* in_sizes, int n_in,
                              void* d_out, int out_size, void* d_ws, size_t ws_size,
                              hipStream_t stream) {
    const float* emb  = (const float*)d_in[0];
    const int*   src  = (const int*)d_in[1];
    const int*   dst  = (const int*)d_in[2];
    const float* vals = (const float*)d_in[3];
    const float* eps  = (const float*)d_in[4];
    const float* W1   = (const float*)d_in[5];
    const float* b1   = (const float*)d_in[6];
    const float* W2   = (const float*)d_in[7];
    const float* b2   = (const float*)d_in[8];
    float* out = (float*)d_out;

    char* ws = (char*)d_ws;
    __bf16* PQ       = (__bf16*)(ws + PQ_OFF);
    float*  partials = (float*)(ws + PART_OFF);

    hipLaunchKernelGGL(node_proj_kernel, dim3((NN + 127) / 128), dim3(256), 0, stream,
                       emb, W1, b1, PQ);
    hipLaunchKernelGGL(edge_kernel, dim3(NBLK_EDGE), dim3(256), 0, stream,
                       PQ, src, dst, vals, eps, W2, b2, out, partials);
    hipLaunchKernelGGL(mean_kernel, dim3(1), dim3(256), 0, stream, partials, out);
}